// Round 8
// baseline (172.878 us; speedup 1.0000x reference)
//
#include <hip/hip_runtime.h>
#include <hip/hip_fp16.h>

typedef unsigned int u32;
typedef unsigned short u16;
typedef int i32x4 __attribute__((ext_vector_type(4)));
typedef float f32x4 __attribute__((ext_vector_type(4)));

#define OUT_F 8192
#define IN_F 8192
#define TOKENS 256
#define N_GROUPS 524288
#define SPLITK 4
#define KSPAN (IN_F / SPLITK)   // 2048 k per split (== 2048 weight-index bytes)
#define KT (KSPAN / 64)         // 32 K-iterations of BK=64

// workspace layout
#define XQ_OFF 0                                         // x int8, 2 MiB
#define T_OFF ((size_t)TOKENS * IN_F)                    // lora partials, 32 KiB
#define SX_OFF (T_OFF + 32768)                           // x scales [2][256] f32
#define NF_OFF (SX_OFF + 2048)                           // norms f16 TRANSPOSED [64][8192], 1 MiB
#define PART_OFF (NF_OFF + (size_t)N_GROUPS * 2)
#define PART_BYTES ((size_t)SPLITK * TOKENS * OUT_F * 4) // 32 MiB
#define WS_NEED (PART_OFF + PART_BYTES)

// code byte b (2-bit codes q0..q3, b in [0,255]) -> u32 of 4 int8 codes 2q-3.
// R7 bug: single-multiply spread (b*0x41041) had overlapping shifted copies ->
// carries (q0+q3>=4, 37.5% of bytes) corrupted q1/q2 => absmax 112. Fix:
// carry-free two-multiply spread (even/odd fields, disjoint bit ranges) +
// arithmetic code map (2q+125 <= 131 per byte, no cross-byte carry; ^0x80
// yields signed {-3,-1,1,3}). Verified by hand: q=[3,0,0,3], q=[1,2,3,0].
__device__ __forceinline__ u32 unpack4(u32 b) {
  u32 e = ((b & 0x33u) * 0x2002u) & 0x00060006u;   // 2*q0 @ byte0, 2*q2 @ byte2
  u32 o = ((b & 0xCCu) * 0x80080u) & 0x06000600u;  // 2*q1 @ byte1, 2*q3 @ byte3
  return ((e | o) + 0x7D7D7D7Du) ^ 0x80808080u;    // per byte: 2q-3 as int8
}

// ---------------------------------------------------------------------------
// prep: blocks [0,512): norm dtype auto-detect (f16/bf16/f32 vote) -> f16,
//       TRANSPOSED to nf[g][n] (g = k/128) so gemm's per-group norm loads are
//       coalesced along n.
//       blocks [512,1024): per (token m, k-half): absmax-quantize x -> int8 xq,
//       scale sx[half][m], and partial t = x . lora_a^T (fp32 exact).
// ---------------------------------------------------------------------------
__global__ __launch_bounds__(256) void prep(const void* __restrict__ wn,
                                            __half* __restrict__ nf,
                                            const float* __restrict__ x,
                                            const float* __restrict__ la,
                                            signed char* __restrict__ xq,
                                            float* __restrict__ sx,
                                            float* __restrict__ t) {
  int tid = threadIdx.x;
  if (blockIdx.x < 512) {
    __shared__ int votes[3];
    __shared__ u16 tile[64][17];
    if (tid < 3) votes[tid] = 0;
    __syncthreads();
    const u16* pu = (const u16*)wn;
    const u32* pw = (const u32*)wn;
    int v16 = 0, vbf = 0, vf = 0;
    for (int i = tid; i < 2048; i += 256) {
      u16 u = pu[i];
      float h = __half2float(__builtin_bit_cast(__half, u));
      float b = __builtin_bit_cast(float, ((u32)u) << 16);
      if (h > 0.008f && h < 1.002f) v16++;
      if (b > 0.008f && b < 1.002f) vbf++;
    }
    for (int i = tid; i < 1024; i += 256) {
      float f = __builtin_bit_cast(float, pw[i]);
      if (f > 0.008f && f < 1.002f) vf++;
    }
    atomicAdd(&votes[0], v16);
    atomicAdd(&votes[1], vbf);
    atomicAdd(&votes[2], vf);
    __syncthreads();
    int a16 = votes[0], abf = votes[1], af32 = 2 * votes[2];
    int mode = (a16 >= abf && a16 >= af32) ? 0 : (abf >= af32 ? 1 : 2);
    // this block: n in [nb, nb+16), g in [0,64); input flat = n*64+g
    int nb = blockIdx.x * 16;
#pragma unroll
    for (int i = 0; i < 4; ++i) {
      int idx = i * 256 + tid;
      int g = idx & 63, nl = idx >> 6;
      int flat = (nb + nl) * 64 + g;
      float v;
      if (mode == 0) v = __half2float(((const __half*)wn)[flat]);
      else if (mode == 1) v = __builtin_bit_cast(float, ((u32)((const u16*)wn)[flat]) << 16);
      else v = ((const float*)wn)[flat];
      tile[g][nl] = __builtin_bit_cast(u16, __float2half(v));
    }
    __syncthreads();
#pragma unroll
    for (int i = 0; i < 4; ++i) {
      int idx = i * 256 + tid;
      int go = idx >> 4, no = idx & 15;
      ((u16*)nf)[(size_t)go * 8192 + nb + no] = tile[go][no];
    }
    return;
  }
  int b2 = blockIdx.x - 512;
  int m = b2 & 255;
  int half = b2 >> 8;
  const float4* xr = (const float4*)(x + (size_t)m * IN_F);
  float4 xv[4];
  float am = 0.f;
  float pl[16];
#pragma unroll
  for (int r = 0; r < 16; ++r) pl[r] = 0.f;
#pragma unroll
  for (int it = 0; it < 4; ++it) {
    int k4 = half * 1024 + it * 256 + tid;
    xv[it] = xr[k4];
    am = fmaxf(am, fmaxf(fmaxf(fabsf(xv[it].x), fabsf(xv[it].y)),
                         fmaxf(fabsf(xv[it].z), fabsf(xv[it].w))));
#pragma unroll
    for (int r = 0; r < 16; ++r) {
      const float4 av = ((const float4*)(la + (size_t)r * IN_F))[k4];
      pl[r] = fmaf(xv[it].x, av.x, pl[r]);
      pl[r] = fmaf(xv[it].y, av.y, pl[r]);
      pl[r] = fmaf(xv[it].z, av.z, pl[r]);
      pl[r] = fmaf(xv[it].w, av.w, pl[r]);
    }
  }
  // reductions
#pragma unroll
  for (int d = 32; d > 0; d >>= 1) am = fmaxf(am, __shfl_xor(am, d));
#pragma unroll
  for (int r = 0; r < 16; ++r) {
    float v = pl[r];
#pragma unroll
    for (int d = 32; d > 0; d >>= 1) v += __shfl_xor(v, d);
    pl[r] = v;
  }
  __shared__ float red[4][16];
  __shared__ float amS[4];
  int wave = tid >> 6, lane = tid & 63;
  if (lane == 0) {
    amS[wave] = am;
#pragma unroll
    for (int r = 0; r < 16; ++r) red[wave][r] = pl[r];
  }
  __syncthreads();
  am = fmaxf(fmaxf(amS[0], amS[1]), fmaxf(amS[2], amS[3]));
  float inv = (am > 1e-20f) ? 127.f / am : 0.f;
  u32* xqw = (u32*)(xq + (size_t)m * IN_F);
#pragma unroll
  for (int it = 0; it < 4; ++it) {
    int k4 = half * 1024 + it * 256 + tid;
    int q0 = (int)rintf(xv[it].x * inv);
    int q1 = (int)rintf(xv[it].y * inv);
    int q2 = (int)rintf(xv[it].z * inv);
    int q3 = (int)rintf(xv[it].w * inv);
    xqw[k4] = (q0 & 255) | ((q1 & 255) << 8) | ((q2 & 255) << 16) | ((q3 & 255) << 24);
  }
  if (tid == 0) sx[half * 256 + m] = am / 127.f;
  if (tid < 16)
    t[((size_t)half * TOKENS + m) * 16 + tid] =
        red[0][tid] + red[1][tid] + red[2][tid] + red[3][tid];
}

// ---------------------------------------------------------------------------
// prep2 (fallback path only): d_out = bias + lora (atomic reduction target).
// ---------------------------------------------------------------------------
__global__ __launch_bounds__(256) void prep2(const float* __restrict__ t,
                                             const float* __restrict__ lb,
                                             const float* __restrict__ bias,
                                             float* __restrict__ out) {
  __shared__ float tS[16 * 16];
  int tid = threadIdx.x;
  int n = blockIdx.x * 256 + tid;
  int mbase = blockIdx.y * 16;
  if (tid < 64) {
    float4 a = ((const float4*)(t + (size_t)mbase * 16))[tid];
    float4 b = ((const float4*)(t + (size_t)TOKENS * 16 + (size_t)mbase * 16))[tid];
    ((float4*)tS)[tid] = make_float4(a.x + b.x, a.y + b.y, a.z + b.z, a.w + b.w);
  }
  const float4* lbp = (const float4*)(lb + (size_t)n * 16);
  float4 b0 = lbp[0], b1 = lbp[1], b2 = lbp[2], b3 = lbp[3];
  float bv = bias[n];
  __syncthreads();
#pragma unroll
  for (int mm = 0; mm < 16; ++mm) {
    const float* tr = &tS[mm * 16];
    float a = bv;
    a += tr[0] * b0.x + tr[1] * b0.y + tr[2] * b0.z + tr[3] * b0.w;
    a += tr[4] * b1.x + tr[5] * b1.y + tr[6] * b1.z + tr[7] * b1.w;
    a += tr[8] * b2.x + tr[9] * b2.y + tr[10] * b2.z + tr[11] * b2.w;
    a += tr[12] * b3.x + tr[13] * b3.y + tr[14] * b3.z + tr[15] * b3.w;
    out[(size_t)(mbase + mm) * OUT_F + n] = a;
  }
}

// ---------------------------------------------------------------------------
// finish (partial path): out = bias + lora + sum_kz partials. No atomics.
// (partials already carry the x-quant scale, applied in gemm epilogue)
// ---------------------------------------------------------------------------
__global__ __launch_bounds__(256) void finish(const float* __restrict__ t,
                                              const float* __restrict__ lb,
                                              const float* __restrict__ bias,
                                              const float* __restrict__ part,
                                              float* __restrict__ out) {
  __shared__ float tS[16 * 16];
  int tid = threadIdx.x;
  int n = blockIdx.x * 256 + tid;
  int mbase = blockIdx.y * 16;
  if (tid < 64) {
    float4 a = ((const float4*)(t + (size_t)mbase * 16))[tid];
    float4 b = ((const float4*)(t + (size_t)TOKENS * 16 + (size_t)mbase * 16))[tid];
    ((float4*)tS)[tid] = make_float4(a.x + b.x, a.y + b.y, a.z + b.z, a.w + b.w);
  }
  const float4* lbp = (const float4*)(lb + (size_t)n * 16);
  float4 b0 = lbp[0], b1 = lbp[1], b2 = lbp[2], b3 = lbp[3];
  float bv = bias[n];
  __syncthreads();
#pragma unroll
  for (int mm = 0; mm < 16; ++mm) {
    const float* tr = &tS[mm * 16];
    float a = bv;
    a += tr[0] * b0.x + tr[1] * b0.y + tr[2] * b0.z + tr[3] * b0.w;
    a += tr[4] * b1.x + tr[5] * b1.y + tr[6] * b1.z + tr[7] * b1.w;
    a += tr[8] * b2.x + tr[9] * b2.y + tr[10] * b2.z + tr[11] * b2.w;
    a += tr[12] * b3.x + tr[13] * b3.y + tr[14] * b3.z + tr[15] * b3.w;
    size_t base = (size_t)(mbase + mm) * OUT_F + n;
#pragma unroll
    for (int kz = 0; kz < SPLITK; ++kz)
      a += part[(size_t)kz * TOKENS * OUT_F + base];
    out[base] = a;
  }
}

// ---------------------------------------------------------------------------
// gemm_q2: int8 MFMA (16x16x64_i8), single-barrier double-buffered K-loop.
// - W codes {-3,-1,1,3} exact in i8 (carry-free unpack4, no LUT);
//   per-128k-group rescale int32 acc -> f32 by norm[n]/3 (norm lane-uniform
//   in C/D cols); x int8 with per-(m,half) scale applied in epilogue.
// - A-frags load DIRECTLY from global xq (2 MiB, L2/L1-hot; 16 rows x 64 B =
//   whole cache lines) -- A never touches LDS. Self-consistent A/B k-ordering
//   makes any HW k-permutation cancel (A/B operand layouts mirror).
// - LDS = B dbuf only (2 x 8 KiB): stage slice kt+1 into Bs[~kt&1] while MFMA
//   reads Bs[kt&1]; ONE barrier/iter, loads issued at top of iter get the
//   whole compute phase as vmcnt cover (the R6 lesson: every __syncthreads
//   drains vmcnt(0), so prefetch distance > 1 barrier-interval is useless).
// ---------------------------------------------------------------------------
__global__ __launch_bounds__(256, 2) void gemm_q2(const signed char* __restrict__ xq,
                                                  const int* __restrict__ wq,
                                                  const __half* __restrict__ nf,
                                                  const float* __restrict__ sx,
                                                  float* __restrict__ dst,
                                                  int mode) {
  __shared__ __align__(16) signed char Bs[2][128 * 64];

  int tid = threadIdx.x;
  int n0 = blockIdx.x * 128;
  int m0 = blockIdx.y * 128;
  int kz = blockIdx.z;
  int kbase = kz * KSPAN;  // k units == bytes of xq row == weight-index bytes of wq

  int wave = tid >> 6, lane = tid & 63;
  int quad = lane >> 4, l15 = lane & 15;
  int mo = (wave & 1) * 64, no = (wave >> 1) * 64;

  // A-frag global base ptrs (per mt): 16 B at [row][kbase + kt*64 + quad*16]
  const signed char* gA[4];
#pragma unroll
  for (int mt = 0; mt < 4; ++mt)
    gA[mt] = xq + (size_t)(m0 + mo + mt * 16 + l15) * IN_F + kbase + quad * 16;

  // B staging: thread -> (row bn, half h): 32 k = 8 int32 words (each word =
  // one code byte = 4 weights; byte address == weight index).
  int bn = tid >> 1, h = tid & 1;
  const signed char* gB = (const signed char*)wq + (size_t)(n0 + bn) * IN_F + kbase + h * 32;
  signed char* myB0 = &Bs[0][bn * 64 + h * 32];
  signed char* myB1 = &Bs[1][bn * 64 + h * 32];

  i32x4 zi = {0, 0, 0, 0};
  f32x4 zf = {0.f, 0.f, 0.f, 0.f};
  i32x4 acc[4][4];
  f32x4 accf[4][4];
#pragma unroll
  for (int i = 0; i < 4; ++i)
#pragma unroll
    for (int j = 0; j < 4; ++j) { acc[i][j] = zi; accf[i][j] = zf; }

  // prologue: A(0) frags; stage B(0) into Bs[0]; load B(1) codes
  i32x4 aF[4], aN[4];
#pragma unroll
  for (int mt = 0; mt < 4; ++mt) aF[mt] = *(const i32x4*)(gA[mt]);
  uint4 w0 = *(const uint4*)(gB);
  uint4 w1 = *(const uint4*)(gB + 16);
  {
    u32 c[8];
    c[0] = unpack4(w0.x); c[1] = unpack4(w0.y); c[2] = unpack4(w0.z); c[3] = unpack4(w0.w);
    c[4] = unpack4(w1.x); c[5] = unpack4(w1.y); c[6] = unpack4(w1.z); c[7] = unpack4(w1.w);
    ((uint4*)myB0)[0] = make_uint4(c[0], c[1], c[2], c[3]);
    ((uint4*)myB0)[1] = make_uint4(c[4], c[5], c[6], c[7]);
  }
  w0 = *(const uint4*)(gB + 64);
  w1 = *(const uint4*)(gB + 80);
  __syncthreads();

#pragma unroll 1
  for (int kt2 = 0; kt2 < KT / 2; ++kt2) {
    int kt = kt2 * 2;

    // ================= even iter kt: read Bs[0]+aF, stage Bs[1] =============
    {
      // issue A(kt+1) at top (covered by this iter's compute)
      if (kt + 1 < KT) {
#pragma unroll
        for (int mt = 0; mt < 4; ++mt)
          aN[mt] = *(const i32x4*)(gA[mt] + (kt + 1) * 64);
      }
      // stage B(kt+1) from regs
      {
        u32 c[8];
        c[0] = unpack4(w0.x); c[1] = unpack4(w0.y); c[2] = unpack4(w0.z); c[3] = unpack4(w0.w);
        c[4] = unpack4(w1.x); c[5] = unpack4(w1.y); c[6] = unpack4(w1.z); c[7] = unpack4(w1.w);
        ((uint4*)myB1)[0] = make_uint4(c[0], c[1], c[2], c[3]);
        ((uint4*)myB1)[1] = make_uint4(c[4], c[5], c[6], c[7]);
      }
      // issue B(kt+2) codes
      if (kt + 2 < KT) {
        w0 = *(const uint4*)(gB + (kt + 2) * 64);
        w1 = *(const uint4*)(gB + (kt + 2) * 64 + 16);
      }
      // compute on Bs[0]
      i32x4 bf[4];
#pragma unroll
      for (int nt = 0; nt < 4; ++nt)
        bf[nt] = *(const i32x4*)(&Bs[0][(no + nt * 16 + l15) * 64 + quad * 16]);
#pragma unroll
      for (int mt = 0; mt < 4; ++mt)
#pragma unroll
        for (int nt = 0; nt < 4; ++nt)
          acc[mt][nt] = __builtin_amdgcn_mfma_i32_16x16x64_i8(aF[mt], bf[nt], acc[mt][nt], 0, 0, 0);
      __syncthreads();
    }

    // ================= odd iter kt+1: read Bs[1]+aN, stage Bs[0] ============
    {
      int ko = kt + 1;
      // issue A(ko+1) at top
      if (ko + 1 < KT) {
#pragma unroll
        for (int mt = 0; mt < 4; ++mt)
          aF[mt] = *(const i32x4*)(gA[mt] + (ko + 1) * 64);
      }
      // norm loads for this group (g = ko>>1), lane-uniform per column
      int g64 = kz * (KSPAN / 128) + (ko >> 1);
      float nrm[4];
#pragma unroll
      for (int nt = 0; nt < 4; ++nt)
        nrm[nt] = __half2float(nf[(size_t)g64 * 8192 + n0 + no + nt * 16 + l15]) * (1.f / 3.f);
      // stage B(ko+1) from regs
      if (ko + 1 < KT) {
        u32 c[8];
        c[0] = unpack4(w0.x); c[1] = unpack4(w0.y); c[2] = unpack4(w0.z); c[3] = unpack4(w0.w);
        c[4] = unpack4(w1.x); c[5] = unpack4(w1.y); c[6] = unpack4(w1.z); c[7] = unpack4(w1.w);
        ((uint4*)myB0)[0] = make_uint4(c[0], c[1], c[2], c[3]);
        ((uint4*)myB0)[1] = make_uint4(c[4], c[5], c[6], c[7]);
      }
      // issue B(ko+2) codes
      if (ko + 2 < KT) {
        w0 = *(const uint4*)(gB + (ko + 2) * 64);
        w1 = *(const uint4*)(gB + (ko + 2) * 64 + 16);
      }
      // compute on Bs[1]
      i32x4 bf[4];
#pragma unroll
      for (int nt = 0; nt < 4; ++nt)
        bf[nt] = *(const i32x4*)(&Bs[1][(no + nt * 16 + l15) * 64 + quad * 16]);
#pragma unroll
      for (int mt = 0; mt < 4; ++mt)
#pragma unroll
        for (int nt = 0; nt < 4; ++nt)
          acc[mt][nt] = __builtin_amdgcn_mfma_i32_16x16x64_i8(aN[mt], bf[nt], acc[mt][nt], 0, 0, 0);
      // group rescale: accf += int_acc * norm[n]/3 ; reset int acc
#pragma unroll
      for (int nt = 0; nt < 4; ++nt)
#pragma unroll
        for (int mt = 0; mt < 4; ++mt) {
#pragma unroll
          for (int r = 0; r < 4; ++r)
            accf[mt][nt][r] = fmaf((float)acc[mt][nt][r], nrm[nt], accf[mt][nt][r]);
          acc[mt][nt] = zi;
        }
      __syncthreads();
    }
  }

  // ---- epilogue: apply x scale (per m, per half = kz>>1), write partials ----
  // C/D layout: row m = quad*4 + reg, col n = lane&15  [m89/m91 verified]
  const float* sxh = sx + (kz >> 1) * 256;
  if (mode) {
    float* pp = dst + (size_t)kz * TOKENS * OUT_F;
#pragma unroll
    for (int mt = 0; mt < 4; ++mt)
#pragma unroll
      for (int r = 0; r < 4; ++r) {
        int mm = m0 + mo + mt * 16 + quad * 4 + r;
        float s = sxh[mm];
#pragma unroll
        for (int nt = 0; nt < 4; ++nt) {
          int nn = n0 + no + nt * 16 + l15;
          pp[(size_t)mm * OUT_F + nn] = accf[mt][nt][r] * s;
        }
      }
  } else {
#pragma unroll
    for (int mt = 0; mt < 4; ++mt)
#pragma unroll
      for (int r = 0; r < 4; ++r) {
        int mm = m0 + mo + mt * 16 + quad * 4 + r;
        float s = sxh[mm];
#pragma unroll
        for (int nt = 0; nt < 4; ++nt) {
          int nn = n0 + no + nt * 16 + l15;
          atomicAdd(&dst[(size_t)mm * OUT_F + nn], accf[mt][nt][r] * s);
        }
      }
  }
}

extern "C" void kernel_launch(void* const* d_in, const int* in_sizes, int n_in,
                              void* d_out, int out_size, void* d_ws, size_t ws_size,
                              hipStream_t stream) {
  (void)in_sizes; (void)n_in; (void)out_size;
  const float* x = (const float*)d_in[0];
  const int* wq = (const int*)d_in[1];
  const void* wn_raw = d_in[2];
  const float* bias = (const float*)d_in[3];
  const float* la = (const float*)d_in[4];
  const float* lb = (const float*)d_in[5];
  float* out = (float*)d_out;

  signed char* xq = (signed char*)((char*)d_ws + XQ_OFF);
  float* t = (float*)((char*)d_ws + T_OFF);
  float* sx = (float*)((char*)d_ws + SX_OFF);
  __half* nf = (__half*)((char*)d_ws + NF_OFF);
  float* part = (float*)((char*)d_ws + PART_OFF);
  int usep = ws_size >= WS_NEED;  // constant per deployment -> graph-safe

  prep<<<1024, 256, 0, stream>>>(wn_raw, nf, x, la, xq, sx, t);
  if (usep) {
    gemm_q2<<<dim3(OUT_F / 128, TOKENS / 128, SPLITK), 256, 0, stream>>>(xq, wq, nf, sx, part, 1);
    finish<<<dim3(OUT_F / 256, TOKENS / 16), 256, 0, stream>>>(t, lb, bias, part, out);
  } else {
    prep2<<<dim3(OUT_F / 256, TOKENS / 16), 256, 0, stream>>>(t, lb, bias, out);
    gemm_q2<<<dim3(OUT_F / 128, TOKENS / 128, SPLITK), 256, 0, stream>>>(xq, wq, nf, sx, out, 0);
  }
}